// Round 7
// baseline (251.521 us; speedup 1.0000x reference)
//
#include <hip/hip_runtime.h>

// Round 19: structural fusion. Evidence: aggS WRITE_SIZE=25MB = 4x the 6.4MB agg
// array — the SPLITS=4 global-atomic combine writes agg back once per split
// (plus gemmD init write + k_final read). aggS runs at its traffic: 112MB@1.7TB/s
// = 66us. Fix: 128-node buckets, ONE block owns each bucket (no splits), sorts
// its ~4096 edges, accumulates in private LDS, then applies the whole epilogue
// (dinv, b1, relu, @Wp+bp, softmax, store) inline. Deleted: agg array, 6.4M
// global f32 atomics, gemmD agg write, k_final (6250-block dispatch).

#define PCHUNK 4096
#define ACH 2048

// ---------- bf16 helpers ----------
__device__ __forceinline__ float bf2f(unsigned int u16) {
    return __uint_as_float(u16 << 16);
}
__device__ __forceinline__ unsigned short f2bf(float f) {
    unsigned int u = __float_as_uint(f);
    u += 0x7fffu + ((u >> 16) & 1u);
    return (unsigned short)(u >> 16);
}

// block-wide vote: is x bf16? (reads first 256 dwords of x, all blocks hit cache)
__device__ __forceinline__ int voteBf16(const unsigned int* xw, int tid, int* scratch) {
    if (tid == 0) *scratch = 0;
    __syncthreads();
    unsigned int w = xw[tid];
    unsigned int lo = w & 0xffffu;
    unsigned int elo = (lo >> 7) & 0xffu;
    if (lo == 0u || (elo >= 100u && elo <= 140u)) atomicAdd(scratch, 1);
    __syncthreads();
    return (*scratch >= 160) ? 1 : 0;
}

// ---------------- kernel: partition edges into fixed-cap 128-node dst-buckets ----------------
// packed entry: s (17 bits) | (d&127) << 17 ; bucket = d>>7 (<= 1024 buckets)
__global__ __launch_bounds__(256) void k_part(const int* __restrict__ ei,
                                              int* __restrict__ cursor,
                                              unsigned int* __restrict__ bkt,
                                              int E, int Nn, int NB2, int cap) {
    __shared__ int lhist[1024];
    __shared__ int lexcl[1024];
    __shared__ int lbase[1024];
    __shared__ int sa[1024], sb[1024];
    __shared__ unsigned int stage[PCHUNK];   // 16 KB
    __shared__ ushort sbk[PCHUNK];           // 8 KB
    __shared__ int stot_s;
    __shared__ int v64_s;
    int tid = threadIdx.x;
    #pragma unroll
    for (int k = 0; k < 4; ++k) lhist[tid + k * 256] = 0;
    if (tid == 0) v64_s = 0;
    __syncthreads();
    // int64 vote: odd dwords of first 256 int64 entries are high words (0 if int64)
    if (((const unsigned int*)ei)[2 * tid + 1] != 0u) atomicAdd(&v64_s, 1);
    __syncthreads();
    int is64 = (v64_s == 0) ? 1 : 0;
    int e0 = blockIdx.x * PCHUNK;
    int ss[16], dd[16];   // dd[i] = d | (rank<<17), or -1
    #pragma unroll
    for (int i = 0; i < 16; ++i) {
        int e = e0 + i * 256 + tid;
        int s = -1, d = -1;
        if (e < E) {
            if (is64) { s = ei[2 * e]; d = ei[2 * (E + e)]; }
            else      { s = ei[e];     d = ei[E + e]; }
            if ((unsigned)s >= (unsigned)Nn || (unsigned)d >= (unsigned)Nn) { s = -1; d = -1; }
        }
        ss[i] = s;
        if (d >= 0) {
            int r = atomicAdd(&lhist[d >> 7], 1);   // rank = arrival order in bucket
            dd[i] = d | (r << 17);                  // d:17b, rank<=4095:12b
        } else dd[i] = -1;
    }
    __syncthreads();
    #pragma unroll
    for (int k = 0; k < 4; ++k) sa[tid + k * 256] = lhist[tid + k * 256];
    __syncthreads();
    int* cur = sa; int* nxt = sb;
    for (int off = 1; off < 1024; off <<= 1) {
        #pragma unroll
        for (int k = 0; k < 4; ++k) {
            int i = tid + k * 256;
            nxt[i] = cur[i] + ((i >= off) ? cur[i - off] : 0);
        }
        __syncthreads();
        int* t = cur; cur = nxt; nxt = t;
    }
    #pragma unroll
    for (int k = 0; k < 4; ++k) {
        int i = tid + k * 256;
        lexcl[i] = cur[i] - lhist[i];
    }
    if (tid == 0) stot_s = cur[1023];
    __syncthreads();
    // reserve runs in fixed-cap buckets
    for (int b = tid; b < 1024; b += 256) {
        int c = lhist[b];
        if (b < NB2 && c > 0) {
            int base = atomicAdd(&cursor[b], c);
            lbase[b] = b * cap + base - lexcl[b];
        } else lbase[b] = 0;
    }
    __syncthreads();
    #pragma unroll
    for (int i = 0; i < 16; ++i) {
        if (dd[i] >= 0) {
            int d = dd[i] & 0x1ffff;
            int b = d >> 7;
            int q = lexcl[b] + (dd[i] >> 17);       // scan base + pass-1 rank
            stage[q] = (unsigned)ss[i] | ((unsigned)(d & 127) << 17);
            sbk[q] = (ushort)b;
        }
    }
    __syncthreads();
    int stot = stot_s;
    for (int q = tid; q < stot; q += 256) {
        int b = sbk[q];
        int pos = lbase[b] + q;
        if (pos < (b + 1) * cap) bkt[pos] = stage[q];   // drop on overflow (cap~48 sigma)
    }
}

// ---------------- kernel: fused per-bucket dinv + gemm (hs only) ----------------
// grid = NB blocks of 256 threads; block b owns nodes [b*256, b*256+256)
// = buckets 2b and 2b+1 of the 128-node bucket space.
__global__ __launch_bounds__(256) void k_gemmD(const void* __restrict__ xraw,
                                               const void* __restrict__ w1raw,
                                               const unsigned int* __restrict__ bkt,
                                               const int* __restrict__ cursor,
                                               float* __restrict__ dinv,
                                               float* __restrict__ hs,
                                               int Nn, int NB2, int cap) {
    __shared__ float sWt[16 * 132];
    __shared__ int ldeg[256];
    __shared__ float sdv[256];
    __shared__ int vote_s;
    const ushort* xb = (const ushort*)xraw;
    const float* xf = (const float*)xraw;
    int tid = threadIdx.x, b = blockIdx.x;
    const int isbf = voteBf16((const unsigned int*)xraw, tid, &vote_s);
    ldeg[tid] = 0;
    if (isbf) {
        const ushort* w1 = (const ushort*)w1raw;
        for (int i = tid; i < 2048; i += 256) {
            int k = i >> 4, j = i & 15;
            sWt[j * 132 + k] = bf2f(w1[i]);
        }
    } else {
        const float* w1 = (const float*)w1raw;
        for (int i = tid; i < 2048; i += 256) {
            int k = i >> 4, j = i & 15;
            sWt[j * 132 + k] = w1[i];
        }
    }
    __syncthreads();
    // phase 1: per-node in-degree from the two half-buckets
    {
        int b0 = 2 * b;
        int len0 = (b0 < NB2) ? min(cursor[b0], cap) : 0;
        size_t bb0 = (size_t)b0 * cap;
        for (int e = tid; e < len0; e += 256)
            atomicAdd(&ldeg[(bkt[bb0 + e] >> 17) & 127u], 1);
        int b1i = 2 * b + 1;
        int len1 = (b1i < NB2) ? min(cursor[b1i], cap) : 0;
        size_t bb1 = (size_t)b1i * cap;
        for (int e = tid; e < len1; e += 256)
            atomicAdd(&ldeg[128 + ((bkt[bb1 + e] >> 17) & 127u)], 1);
    }
    __syncthreads();
    {
        float dv = rsqrtf((float)(ldeg[tid] + 1));  // +1 self loop
        sdv[tid] = dv;
        int n = (b << 8) + tid;
        if (n < Nn) dinv[n] = dv;
    }
    __syncthreads();
    // phase 2: gemm (round-8 non-spilling form)
    int hq = tid & 3;
    int nodeq = tid >> 2;
    int n0 = (b << 8) + nodeq * 4;
    float acc[4][4] = {};
    for (int ko = 0; ko < 16; ++ko) {
        float xv[4][8];
        #pragma unroll
        for (int r = 0; r < 4; ++r) {
            int n = n0 + r;
            if (n < Nn) {
                if (isbf) {
                    uint4 q = *reinterpret_cast<const uint4*>(xb + (size_t)n * 128 + ko * 8);
                    xv[r][0] = bf2f(q.x & 0xffffu); xv[r][1] = bf2f(q.x >> 16);
                    xv[r][2] = bf2f(q.y & 0xffffu); xv[r][3] = bf2f(q.y >> 16);
                    xv[r][4] = bf2f(q.z & 0xffffu); xv[r][5] = bf2f(q.z >> 16);
                    xv[r][6] = bf2f(q.w & 0xffffu); xv[r][7] = bf2f(q.w >> 16);
                } else {
                    const float4* p = reinterpret_cast<const float4*>(xf + (size_t)n * 128 + ko * 8);
                    float4 a = p[0], bf = p[1];
                    xv[r][0] = a.x; xv[r][1] = a.y; xv[r][2] = a.z; xv[r][3] = a.w;
                    xv[r][4] = bf.x; xv[r][5] = bf.y; xv[r][6] = bf.z; xv[r][7] = bf.w;
                }
            } else {
                #pragma unroll
                for (int u = 0; u < 8; ++u) xv[r][u] = 0.f;
            }
        }
        #pragma unroll
        for (int c = 0; c < 4; ++c) {
            const float* wr = &sWt[(hq * 4 + c) * 132 + ko * 8];
            float4 w0 = *reinterpret_cast<const float4*>(wr);
            float4 w1v = *reinterpret_cast<const float4*>(wr + 4);
            #pragma unroll
            for (int r = 0; r < 4; ++r) {
                acc[r][c] += xv[r][0] * w0.x + xv[r][1] * w0.y + xv[r][2] * w0.z + xv[r][3] * w0.w
                           + xv[r][4] * w1v.x + xv[r][5] * w1v.y + xv[r][6] * w1v.z + xv[r][7] * w1v.w;
            }
        }
    }
    #pragma unroll
    for (int r = 0; r < 4; ++r) {
        int n = n0 + r;
        if (n < Nn) {
            float dv = sdv[nodeq * 4 + r];
            float4 o = make_float4(acc[r][0] * dv, acc[r][1] * dv, acc[r][2] * dv, acc[r][3] * dv);
            *reinterpret_cast<float4*>(hs + (size_t)n * 16 + hq * 4) = o;
        }
    }
}

// ---------------- kernel: fused bucket agg + epilogue (owns its 128 nodes) ----------------
// grid = NB2 blocks of 256; block b sorts bucket b's edges (chunks of ACH),
// segment-accumulates into private sAgg, then applies dinv+b1+relu -> @Wp+bp
// -> softmax -> store. No global agg array, no atomics.
__global__ __launch_bounds__(256) void k_aggF(const unsigned int* __restrict__ bkt,
                                              const int* __restrict__ cursor,
                                              const float* __restrict__ hs,
                                              const float* __restrict__ dinv,
                                              const void* __restrict__ xraw,
                                              const void* __restrict__ b1raw,
                                              const void* __restrict__ wpraw,
                                              const void* __restrict__ bpraw,
                                              void* __restrict__ outraw,
                                              int Nn, int cap) {
    __shared__ float sAgg[2048];          // 8 KB
    __shared__ unsigned int sSorted[ACH]; // 8 KB
    __shared__ int cnt[128], excl[128];
    __shared__ int sc[2][128];
    __shared__ float sWp[256];
    __shared__ float sA[256];
    __shared__ int tot_s, vote_s;
    int tid = threadIdx.x, b = blockIdx.x;
    const int isbf = voteBf16((const unsigned int*)xraw, tid, &vote_s);
    sWp[tid] = isbf ? bf2f(((const ushort*)wpraw)[tid]) : ((const float*)wpraw)[tid];
    for (int i = tid; i < 2048; i += 256) sAgg[i] = 0.f;
    int len = min(cursor[b], cap);
    size_t bb = (size_t)b * cap;
    int g = tid >> 4, j = tid & 15;
    for (int c0 = 0; c0 < len; c0 += ACH) {
        if (tid < 128) cnt[tid] = 0;
        __syncthreads();
        unsigned ue[8];
        int rr[8];
        #pragma unroll
        for (int i = 0; i < 8; ++i) {
            int idx = c0 + i * 256 + tid;
            if (idx < len) {
                ue[i] = bkt[bb + idx];
                rr[i] = atomicAdd(&cnt[(ue[i] >> 17) & 127u], 1);  // rank
            } else { ue[i] = 0xffffffffu; rr[i] = 0; }
        }
        __syncthreads();
        int v = (tid < 128) ? cnt[tid] : 0;
        if (tid < 128) sc[0][tid] = v;
        __syncthreads();
        int pi = 0;
        for (int off = 1; off < 128; off <<= 1) {
            if (tid < 128) sc[pi ^ 1][tid] = sc[pi][tid] + ((tid >= off) ? sc[pi][tid - off] : 0);
            __syncthreads();
            pi ^= 1;
        }
        if (tid < 128) excl[tid] = sc[pi][tid] - v;
        if (tid == 127) tot_s = sc[pi][127];
        __syncthreads();
        #pragma unroll
        for (int i = 0; i < 8; ++i) {
            if (ue[i] != 0xffffffffu)
                sSorted[excl[(ue[i] >> 17) & 127u] + rr[i]] = ue[i];
        }
        __syncthreads();
        int tot = tot_s;
        // 8-wide branch-free per-node segment accumulate (group g owns nodes g*8..g*8+8)
        #pragma unroll 2
        for (int nn = 0; nn < 8; ++nn) {
            int node = g * 8 + nn;
            int segS = excl[node];
            int segE = (node == 127) ? tot : excl[node + 1];
            float acc = 0.f;
            #pragma unroll 1
            for (int base = segS; base < segE; base += 8) {
                int m = segE - base;
                unsigned e8[8];
                float vv[8];
                #pragma unroll
                for (int i = 0; i < 8; ++i) {
                    int idx = base + i;
                    e8[i] = sSorted[(idx < segE) ? idx : segS];  // clamp inside segment
                }
                #pragma unroll
                for (int i = 0; i < 8; ++i)
                    vv[i] = hs[(size_t)(e8[i] & 0x1ffffu) * 16 + j];  // independent gathers
                #pragma unroll
                for (int i = 0; i < 8; ++i)
                    vv[i] = (i < m) ? vv[i] : 0.f;
                vv[0] += vv[4]; vv[1] += vv[5]; vv[2] += vv[6]; vv[3] += vv[7];
                vv[0] += vv[2]; vv[1] += vv[3];
                acc += vv[0] + vv[1];
            }
            if (segE > segS) sAgg[node * 16 + j] += acc;  // plain RMW: group owns node
        }
        __syncthreads();
    }
    __syncthreads();
    // fused epilogue: dinv*(self+agg)+b1 -> relu -> @Wp+bp -> softmax -> out
    int nl = tid >> 4, c = tid & 15;
    float b1v = isbf ? bf2f(((const ushort*)b1raw)[c]) : ((const float*)b1raw)[c];
    float bpv = isbf ? bf2f(((const ushort*)bpraw)[c]) : ((const float*)bpraw)[c];
    int nbase = b << 7;
    #pragma unroll 1
    for (int pass = 0; pass < 8; ++pass) {
        int node = pass * 16 + nl;
        int n = nbase + node;
        float dv = 0.f, sv = 0.f;
        if (n < Nn) { dv = dinv[n]; sv = hs[(size_t)n * 16 + c]; }
        float hval = fmaxf(dv * (sv + sAgg[node * 16 + c]) + b1v, 0.f);
        sA[tid] = hval;
        __syncthreads();
        float acc = bpv;
        #pragma unroll
        for (int jj = 0; jj < 16; ++jj) acc += sA[nl * 16 + jj] * sWp[jj * 16 + c];
        float m = acc;
        #pragma unroll
        for (int off = 1; off < 16; off <<= 1) m = fmaxf(m, __shfl_xor(m, off, 16));
        float ev = __expf(acc - m);
        float s = ev;
        #pragma unroll
        for (int off = 1; off < 16; off <<= 1) s += __shfl_xor(s, off, 16);
        if (n < Nn) {
            float val = ev / s;
            if (isbf) ((ushort*)outraw)[(size_t)n * 16 + c] = f2bf(val);
            else      ((float*)outraw)[(size_t)n * 16 + c] = val;
        }
        __syncthreads();
    }
}

extern "C" void kernel_launch(void* const* d_in, const int* in_sizes, int n_in,
                              void* d_out, int out_size, void* d_ws, size_t ws_size,
                              hipStream_t stream) {
    const void* x  = d_in[0];
    const void* W1 = d_in[1];
    const void* b1 = d_in[2];
    const void* Wp = d_in[3];
    const void* bp = d_in[4];
    const int*  ei = (const int*)d_in[5];

    int Nn  = in_sizes[0] / 128;
    int E   = in_sizes[5] / 2;
    int NB  = (Nn + 255) >> 8;   // gemmD blocks (256 nodes)
    int NB2 = (Nn + 127) >> 7;   // buckets (128 nodes)

    size_t Ns = (size_t)Nn;
    char* ws = (char*)d_ws;
    size_t off = 0;
    auto alloc = [&](size_t bytes) { void* p = ws + off; off += (bytes + 63) & ~(size_t)63; return p; };
    float* hs     = (float*)alloc(Ns * 16 * 4);
    float* dinv   = (float*)alloc(Ns * 4);
    int*   cursor = (int*)alloc(1024 * 4);
    // adaptive fixed bucket capacity (mean fill ~E/NB2, want 1.5x => ~48 sigma)
    size_t remain = (ws_size > off) ? (ws_size - off) : 0;
    int cap = (int)(remain / 4 / (size_t)NB2);
    int want = 6144;
    if (cap > want) cap = want;
    cap &= ~63;
    unsigned int* bkt = (unsigned int*)alloc((size_t)NB2 * (size_t)cap * 4);

    hipMemsetAsync(cursor, 0, 1024 * 4, stream);
    k_part<<<(E + PCHUNK - 1) / PCHUNK, 256, 0, stream>>>(ei, cursor, bkt, E, Nn, NB2, cap);
    k_gemmD<<<NB, 256, 0, stream>>>(x, W1, bkt, cursor, dinv, hs, Nn, NB2, cap);
    k_aggF<<<NB2, 256, 0, stream>>>(bkt, cursor, hs, dinv, x, b1, Wp, bp, d_out, Nn, cap);
}